// Round 1
// 1103.420 us; speedup vs baseline: 1.0706x; 1.0706x over previous
//
#include <hip/hip_runtime.h>
#include <math.h>

#define BB 4
#define NN 1024
#define DD 1024
#define EE 32
#define HH 4096

// workspace offsets (in floats)
#define Q_OFF      0         // [32][1024]
#define LOGITS_OFF 32768     // [4][1024][32]
#define DWT_OFF    163840    // [4][32][1024]  dispatch weights transposed
#define CW_OFF     294912    // [4][1024][32]  combine weights
#define SLOTS_OFF  425984    // [4][32][1024]  reduced slots
#define SPART_OFF  557056    // [32][4][32][1024] slot partials (per n-tile)
#define HPART_OFF  4751360   // [4][32][4][4096]  h partials (per d-chunk)
#define EPART_OFF  6848512   // [16][4][32][1024] eo partials (per h-chunk)
#define EO_OFF     8945664   // [4][32][1024]
#define MACC_OFF   9076736   // [4] metric accumulators
#define WS_TOTAL   9076740

// ---------------- q = LayerNorm(phi*qg+qb)*lng+lnb, * scale ----------------
__global__ __launch_bounds__(256) void q_kernel(
    const float* __restrict__ phi, const float* __restrict__ qg,
    const float* __restrict__ qb, const float* __restrict__ lng,
    const float* __restrict__ lnb, const float* __restrict__ scale,
    float* __restrict__ q)
{
    int e = blockIdx.x, t = threadIdx.x;
    float v[4]; float s = 0.f, s2 = 0.f;
    #pragma unroll
    for (int i = 0; i < 4; ++i) {
        int d = i*256 + t;
        float xv = phi[e*DD + d]*qg[d] + qb[d];
        v[i] = xv; s += xv; s2 += xv*xv;
    }
    #pragma unroll
    for (int o = 32; o > 0; o >>= 1) { s += __shfl_xor(s, o); s2 += __shfl_xor(s2, o); }
    __shared__ float ra[4], rb[4];
    if ((t & 63) == 0) { ra[t>>6] = s; rb[t>>6] = s2; }
    __syncthreads();
    s  = ra[0]+ra[1]+ra[2]+ra[3];
    s2 = rb[0]+rb[1]+rb[2]+rb[3];
    float mean = s * (1.f/DD);
    float var  = s2 * (1.f/DD) - mean*mean;
    float r = rsqrtf(var + 1e-5f);
    float sc = scale[0];
    #pragma unroll
    for (int i = 0; i < 4; ++i) {
        int d = i*256 + t;
        q[e*DD + d] = ((v[i]-mean)*r*lng[d] + lnb[d]) * sc;
    }
}

// ---------------- logits[b][n][e] = sum_d (x*kg+kb) * q[e][d] ----------------
// one wave per row, 4 rows/block
__global__ __launch_bounds__(256) void logits_kernel(
    const float* __restrict__ x, const float* __restrict__ kg,
    const float* __restrict__ kb, const float* __restrict__ q,
    float* __restrict__ logits)
{
    int w = threadIdx.x >> 6, l = threadIdx.x & 63;
    int row = blockIdx.x*4 + w;                 // 0..4095 = b*1024+n
    const float* xr = x + (size_t)row * DD;
    float acc[EE];
    #pragma unroll
    for (int e = 0; e < EE; ++e) acc[e] = 0.f;
    #pragma unroll
    for (int i = 0; i < 4; ++i) {
        int d0 = i*256 + l*4;
        float4 xv = *(const float4*)(xr + d0);
        float4 g  = *(const float4*)(kg + d0);
        float4 bv = *(const float4*)(kb + d0);
        float4 kv;
        kv.x = xv.x*g.x + bv.x; kv.y = xv.y*g.y + bv.y;
        kv.z = xv.z*g.z + bv.z; kv.w = xv.w*g.w + bv.w;
        #pragma unroll
        for (int e = 0; e < EE; ++e) {
            float4 qv = *(const float4*)(q + e*DD + d0);
            acc[e] += kv.x*qv.x + kv.y*qv.y + kv.z*qv.z + kv.w*qv.w;
        }
    }
    #pragma unroll
    for (int e = 0; e < EE; ++e) {
        float a = acc[e];
        #pragma unroll
        for (int o = 32; o > 0; o >>= 1) a += __shfl_xor(a, o);
        if (l == 0) logits[(size_t)row*EE + e] = a;
    }
}

// ---------------- dispatch softmax over N per (b,e), + dw similarity metric ----------------
__global__ __launch_bounds__(256) void dsoftmax_kernel(
    const float* __restrict__ logits, float* __restrict__ dwT,
    float* __restrict__ macc)
{
    int be = blockIdx.x; int b = be >> 5, e = be & 31;
    int t = threadIdx.x;
    __shared__ float red[4];
    const float* lb = logits + (size_t)b*NN*EE + e;
    float v[4]; float m = -1e30f;
    #pragma unroll
    for (int i = 0; i < 4; ++i) {
        v[i] = lb[(size_t)(i*256 + t)*EE];
        m = fmaxf(m, v[i]);
    }
    #pragma unroll
    for (int o = 32; o > 0; o >>= 1) m = fmaxf(m, __shfl_xor(m, o));
    if ((t & 63) == 0) red[t>>6] = m;
    __syncthreads();
    m = fmaxf(fmaxf(red[0], red[1]), fmaxf(red[2], red[3]));
    __syncthreads();
    float p[4]; float z = 0.f;
    #pragma unroll
    for (int i = 0; i < 4; ++i) { p[i] = expf(v[i]-m); z += p[i]; }
    #pragma unroll
    for (int o = 32; o > 0; o >>= 1) z += __shfl_xor(z, o);
    if ((t & 63) == 0) red[t>>6] = z;
    __syncthreads();
    z = red[0]+red[1]+red[2]+red[3];
    __syncthreads();
    float rz = 1.f / z;
    float s2 = 0.f;
    float* dp = dwT + ((size_t)b*EE + e)*NN;
    #pragma unroll
    for (int i = 0; i < 4; ++i) {
        float pv = p[i]*rz;
        dp[i*256+t] = pv;
        s2 += pv*pv;
    }
    #pragma unroll
    for (int o = 32; o > 0; o >>= 1) s2 += __shfl_xor(s2, o);
    if ((t & 63) == 0) red[t>>6] = s2;
    __syncthreads();
    if (t == 0) {
        float tot = red[0]+red[1]+red[2]+red[3];
        float rd2 = 1.f / (tot + 1e-9f);   // RD^2 = (sum dn)^2 = 1/(s2+eps), sum p == 1
        atomicAdd(&macc[2], rd2);
        if (e == 0) atomicAdd(&macc[3], rd2);
    }
}

// ---------------- combine softmax over E per (b,n), + cw similarity metric ----------------
// 8 rows/block, 32 lanes per row
__global__ __launch_bounds__(256) void csoftmax_kernel(
    const float* __restrict__ logits, float* __restrict__ cw,
    float* __restrict__ macc)
{
    int t = threadIdx.x, sub = t >> 5, e = t & 31;
    int row = blockIdx.x*8 + sub;               // 0..4095
    float v = logits[(size_t)row*EE + e];
    float m = v;
    #pragma unroll
    for (int o = 16; o > 0; o >>= 1) m = fmaxf(m, __shfl_xor(m, o));
    float p = expf(v - m);
    float z = p;
    #pragma unroll
    for (int o = 16; o > 0; o >>= 1) z += __shfl_xor(z, o);
    p = p / z;
    cw[(size_t)row*EE + e] = p;
    float s2 = p*p, s1 = p;
    #pragma unroll
    for (int o = 16; o > 0; o >>= 1) { s2 += __shfl_xor(s2, o); s1 += __shfl_xor(s1, o); }
    float r = rsqrtf(s2 + 1e-9f);
    float cf = p*r, R = s1*r;
    __shared__ float rr[8];
    if (e == 0) rr[sub] = R*R;
    __syncthreads();
    if (t == 0) atomicAdd(&macc[0], rr[0]+rr[1]+rr[2]+rr[3]+rr[4]+rr[5]+rr[6]+rr[7]);
    int n = row & (NN-1);
    if (n < EE && e == n) atomicAdd(&macc[1], cf*R);   // cf[b,n,n]*R[b,n]
}

// ---------------- spart[nt][b][e][d] = sum_{n in tile nt} x[b][n][d]*dw[b][n][e] ----------------
// plain stores to per-tile partials (no atomics)
__global__ __launch_bounds__(256) void slots_kernel(
    const float* __restrict__ x, const float* __restrict__ dwT,
    float* __restrict__ spart)
{
    int nt = blockIdx.x;          // 32 tiles of 32 rows
    int e0 = blockIdx.y * 16;
    int b  = blockIdx.z;
    int t = threadIdx.x;
    __shared__ float wv[16][32];
    for (int i = t; i < 512; i += 256) {
        int e = i >> 5, n = i & 31;
        wv[e][n] = dwT[((size_t)b*EE + e0 + e)*NN + nt*32 + n];
    }
    __syncthreads();
    float4 acc[16];
    #pragma unroll
    for (int e = 0; e < 16; ++e) acc[e] = make_float4(0.f,0.f,0.f,0.f);
    const float* xb = x + (size_t)b*NN*DD + (size_t)(nt*32)*DD + t*4;
    for (int n = 0; n < 32; ++n) {
        float4 xv = *(const float4*)(xb + (size_t)n*DD);
        #pragma unroll
        for (int e = 0; e < 16; ++e) {
            float wgt = wv[e][n];
            acc[e].x += wgt*xv.x; acc[e].y += wgt*xv.y;
            acc[e].z += wgt*xv.z; acc[e].w += wgt*xv.w;
        }
    }
    #pragma unroll
    for (int e = 0; e < 16; ++e) {
        *(float4*)(spart + (((size_t)nt*BB + b)*EE + e0 + e)*DD + t*4) = acc[e];
    }
}

// ---------------- slots[b][e][d] = sum_nt spart[nt][b][e][d] ----------------
__global__ __launch_bounds__(256) void sreduce_kernel(
    const float* __restrict__ spart, float* __restrict__ slots)
{
    int j = (blockIdx.x*256 + threadIdx.x)*4;   // 0..131068
    float4 a = make_float4(0.f,0.f,0.f,0.f);
    #pragma unroll
    for (int nt = 0; nt < 32; ++nt) {
        float4 v = *(const float4*)(spart + (size_t)nt*(BB*EE*DD) + j);
        a.x += v.x; a.y += v.y; a.z += v.z; a.w += v.w;
    }
    *(float4*)(slots + j) = a;
}

// ---------------- hpart[kt][e][b][h] = sum_{d in chunk kt} slots[b][e][d]*w1[e][d][h] ----------------
// kt = 4 chunks of 256 d; plain stores (no atomics)
__global__ __launch_bounds__(256) void w1_kernel(
    const float* __restrict__ slots, const float* __restrict__ w1,
    float* __restrict__ hpart)
{
    int kt = blockIdx.x;      // 0..3, d-chunk of 256
    int ht = blockIdx.y;      // 0..3, h-chunk of 1024
    int e  = blockIdx.z;
    int t = threadIdx.x;
    __shared__ __align__(16) float sT[256][4];
    for (int i = t; i < 1024; i += 256) {
        int b = i >> 8, d = i & 255;
        sT[d][b] = slots[((size_t)b*EE + e)*DD + kt*256 + d];
    }
    __syncthreads();
    int h0 = ht*1024 + t*4;
    float4 a0 = make_float4(0.f,0.f,0.f,0.f), a1 = a0, a2 = a0, a3 = a0;
    const float* wp = w1 + ((size_t)e*DD + kt*256)*HH + h0;
    #pragma unroll 8
    for (int d = 0; d < 256; ++d) {
        float4 w = *(const float4*)(wp + (size_t)d*HH);
        float4 s = *(const float4*)(&sT[d][0]);
        a0.x += s.x*w.x; a0.y += s.x*w.y; a0.z += s.x*w.z; a0.w += s.x*w.w;
        a1.x += s.y*w.x; a1.y += s.y*w.y; a1.z += s.y*w.z; a1.w += s.y*w.w;
        a2.x += s.z*w.x; a2.y += s.z*w.y; a2.z += s.z*w.z; a2.w += s.z*w.w;
        a3.x += s.w*w.x; a3.y += s.w*w.y; a3.z += s.w*w.z; a3.w += s.w*w.w;
    }
    float* hp = hpart + (((size_t)kt*EE + e)*BB)*HH + h0;
    *(float4*)(hp)        = a0;
    *(float4*)(hp + HH)   = a1;
    *(float4*)(hp + 2*HH) = a2;
    *(float4*)(hp + 3*HH) = a3;
}

// ---------------- epart[kt][b][e][d] = sum_{h in chunk kt} gelu(sum_k hpart + b1)*w2[e][h][d] ----------------
// gelu + 4-partial reduce fused into the LDS staging; plain stores (no atomics)
__global__ __launch_bounds__(256) void w2_kernel(
    const float* __restrict__ hpart, const float* __restrict__ b1,
    const float* __restrict__ w2, float* __restrict__ epart)
{
    int kt = blockIdx.x;   // 0..15, h-chunk of 256
    int e  = blockIdx.y;
    int t = threadIdx.x;
    __shared__ __align__(16) float gT[256][4];
    for (int i = t; i < 1024; i += 256) {
        int b = i >> 8, h = i & 255;
        int habs = kt*256 + h;
        float v = b1[(size_t)e*HH + habs];
        #pragma unroll
        for (int k = 0; k < 4; ++k)
            v += hpart[(((size_t)k*EE + e)*BB + b)*HH + habs];
        gT[h][b] = 0.5f * v * (1.f + erff(v * 0.70710678118654752f));
    }
    __syncthreads();
    int d0 = t*4;
    float4 a0 = make_float4(0.f,0.f,0.f,0.f), a1 = a0, a2 = a0, a3 = a0;
    const float* wp = w2 + ((size_t)e*HH + kt*256)*DD + d0;
    #pragma unroll 8
    for (int h = 0; h < 256; ++h) {
        float4 w = *(const float4*)(wp + (size_t)h*DD);
        float4 g = *(const float4*)(&gT[h][0]);
        a0.x += g.x*w.x; a0.y += g.x*w.y; a0.z += g.x*w.z; a0.w += g.x*w.w;
        a1.x += g.y*w.x; a1.y += g.y*w.y; a1.z += g.y*w.z; a1.w += g.y*w.w;
        a2.x += g.z*w.x; a2.y += g.z*w.y; a2.z += g.z*w.z; a2.w += g.z*w.w;
        a3.x += g.w*w.x; a3.y += g.w*w.y; a3.z += g.w*w.z; a3.w += g.w*w.w;
    }
    #pragma unroll
    for (int b = 0; b < 4; ++b) {
        float4 a = (b==0)?a0:(b==1)?a1:(b==2)?a2:a3;
        *(float4*)(epart + (((size_t)kt*BB + b)*EE + e)*DD + d0) = a;
    }
}

// ---------------- eo[b][e][d] = sum_kt epart[kt][b][e][d] + b2[e][d] ----------------
__global__ __launch_bounds__(256) void b2red_kernel(
    const float* __restrict__ epart, const float* __restrict__ b2,
    float* __restrict__ eo)
{
    int j = (blockIdx.x*256 + threadIdx.x)*4;   // 0..131068, j = b*32768 + e*1024 + d
    float4 a = *(const float4*)(b2 + (j & 32767));
    #pragma unroll
    for (int kt = 0; kt < 16; ++kt) {
        float4 v = *(const float4*)(epart + (size_t)kt*(BB*EE*DD) + j);
        a.x += v.x; a.y += v.y; a.z += v.z; a.w += v.w;
    }
    *(float4*)(eo + j) = a;
}

// ---------------- out[b][n][d] = sum_e cw[b][n][e]*eo[b][e][d] ----------------
__global__ __launch_bounds__(256) void combine_kernel(
    const float* __restrict__ cw, const float* __restrict__ eo,
    float* __restrict__ out)
{
    int nt = blockIdx.x;        // 64 tiles of 16 rows
    int b  = blockIdx.y;
    int t = threadIdx.x;
    __shared__ __align__(16) float cwl[16][32];
    for (int i = t; i < 512; i += 256) {
        int r = i >> 5, e = i & 31;
        cwl[r][e] = cw[((size_t)b*NN + nt*16 + r)*EE + e];
    }
    __syncthreads();
    float4 acc[16];
    #pragma unroll
    for (int r = 0; r < 16; ++r) acc[r] = make_float4(0.f,0.f,0.f,0.f);
    const float* ep = eo + (size_t)b*EE*DD + t*4;
    #pragma unroll
    for (int e4 = 0; e4 < 8; ++e4) {
        float4 w0 = *(const float4*)(ep + (size_t)(e4*4+0)*DD);
        float4 w1v = *(const float4*)(ep + (size_t)(e4*4+1)*DD);
        float4 w2v = *(const float4*)(ep + (size_t)(e4*4+2)*DD);
        float4 w3v = *(const float4*)(ep + (size_t)(e4*4+3)*DD);
        #pragma unroll
        for (int r = 0; r < 16; ++r) {
            float4 c = *(const float4*)(&cwl[r][e4*4]);
            acc[r].x += c.x*w0.x + c.y*w1v.x + c.z*w2v.x + c.w*w3v.x;
            acc[r].y += c.x*w0.y + c.y*w1v.y + c.z*w2v.y + c.w*w3v.y;
            acc[r].z += c.x*w0.z + c.y*w1v.z + c.z*w2v.z + c.w*w3v.z;
            acc[r].w += c.x*w0.w + c.y*w1v.w + c.z*w2v.w + c.w*w3v.w;
        }
    }
    #pragma unroll
    for (int r = 0; r < 16; ++r) {
        *(float4*)(out + ((size_t)b*NN + nt*16 + r)*DD + t*4) = acc[r];
    }
}

// ---------------- finalize metrics ----------------
__global__ void finalize_kernel(const float* __restrict__ macc, float* __restrict__ out)
{
    out[4194304] = (macc[0] - macc[1]) * (1.f / 4190208.f);  // B*N*(N-1)
    out[4194305] = (macc[2] - macc[3]) * (1.f / 3968.f);     // B*E*S*(E*S-1)
}

extern "C" void kernel_launch(void* const* d_in, const int* in_sizes, int n_in,
                              void* d_out, int out_size, void* d_ws, size_t ws_size,
                              hipStream_t stream) {
    const float* x   = (const float*)d_in[0];
    const float* phi = (const float*)d_in[1];
    const float* kg  = (const float*)d_in[2];
    const float* kb  = (const float*)d_in[3];
    const float* qg  = (const float*)d_in[4];
    const float* qb  = (const float*)d_in[5];
    const float* lng = (const float*)d_in[6];
    const float* lnb = (const float*)d_in[7];
    const float* sc  = (const float*)d_in[8];
    const float* w1  = (const float*)d_in[9];
    const float* b1  = (const float*)d_in[10];
    const float* w2  = (const float*)d_in[11];
    const float* b2  = (const float*)d_in[12];
    float* out = (float*)d_out;
    float* ws  = (float*)d_ws;

    float* q      = ws + Q_OFF;
    float* logits = ws + LOGITS_OFF;
    float* dwT    = ws + DWT_OFF;
    float* cw     = ws + CW_OFF;
    float* slots  = ws + SLOTS_OFF;
    float* spart  = ws + SPART_OFF;
    float* hpart  = ws + HPART_OFF;
    float* epart  = ws + EPART_OFF;
    float* eo     = ws + EO_OFF;
    float* macc   = ws + MACC_OFF;

    // only the 4 metric accumulators need zeroing now (no hot-path atomics left)
    hipMemsetAsync(macc, 0, 4*sizeof(float), stream);

    q_kernel<<<32, 256, 0, stream>>>(phi, qg, qb, lng, lnb, sc, q);
    logits_kernel<<<1024, 256, 0, stream>>>(x, kg, kb, q, logits);
    dsoftmax_kernel<<<128, 256, 0, stream>>>(logits, dwT, macc);
    csoftmax_kernel<<<512, 256, 0, stream>>>(logits, cw, macc);
    slots_kernel<<<dim3(32,2,4), 256, 0, stream>>>(x, dwT, spart);
    sreduce_kernel<<<128, 256, 0, stream>>>(spart, slots);
    w1_kernel<<<dim3(4,4,32), 256, 0, stream>>>(slots, w1, hpart);
    w2_kernel<<<dim3(16,32), 256, 0, stream>>>(hpart, b1, w2, epart);
    b2red_kernel<<<128, 256, 0, stream>>>(epart, b2, eo);
    combine_kernel<<<dim3(64,4), 256, 0, stream>>>(cw, eo, out);
    finalize_kernel<<<1, 1, 0, stream>>>(macc, out);
}